// Round 2
// baseline (670.557 us; speedup 1.0000x reference)
//
#include <hip/hip_runtime.h>
#include <stdint.h>

// ---------------------------------------------------------------------------
// MultichannelMultiheadAttention: B=2,C=8,F=1024,W=512,NH=8,HD=128
// cvt(W_lin->bf16) ; conv3x3(q,k,v, proj-serialized) -> per-channel linear
// (bf16 MFMA GEMM) -> RoPE -> fused flash-style attention (S=QK^T/32+prev,
// qk written, softmax WITHOUT max-subtraction [|scores|<1 by construction],
// PV accumulate) -> out linear.
// R2: k_attn occupancy-first: Q LDS staging dropped (L2-resident direct
// frags), LDS 68.6->35.8 KB, VGPR trimmed (8-float prev chunks, single live
// B-frag) + __launch_bounds__(256,3) -> 3 blocks/CU; setprio around MFMA;
// bijective XCD swizzle grouping the 4 qt of each bcn on one XCD.
// ---------------------------------------------------------------------------

typedef float f32x4 __attribute__((ext_vector_type(4)));
typedef short s16x8 __attribute__((ext_vector_type(8)));

__device__ __forceinline__ short f2bf(float f) {
  union { float f; uint32_t u; } v; v.f = f;
  uint32_t r = v.u + 0x7FFFu + ((v.u >> 16) & 1u);  // RNE
  return (short)(r >> 16);
}

__device__ __forceinline__ void g2l16(const void* g, void* l) {
  __builtin_amdgcn_global_load_lds(
      (const __attribute__((address_space(1))) void*)g,
      (__attribute__((address_space(3))) void*)l, 16, 0, 0);
}

// ---------------------------------------------------------------------------
// GEMM core: C[128x128] = A(128xK) * B^T, B stored (128 x K), both bf16
// row-major K-contiguous. 256 thr, 2x2 waves, 4x4 frags of 16x16x32.
// (used by k_qkv / k_out)
// ---------------------------------------------------------------------------
__device__ __forceinline__ void gemm_core(const short* __restrict__ A,
                                          const short* __restrict__ B,
                                          int K, short* sA, short* sB,
                                          f32x4 (*acc)[4]) {
  const int tid = threadIdx.x;
  const int lane = tid & 63;
  const int wv = tid >> 6;
  const int wm = wv >> 1, wn = wv & 1;
  const int q = lane >> 4, cix = lane & 15;

  for (int k0 = 0; k0 < K; k0 += 32) {
    __syncthreads();
#pragma unroll
    for (int i = 0; i < 2; ++i) {
      int seg = wv + 4 * i;  // wave-uniform LDS base
      int m = seg * 16 + (lane >> 2);
      int ko = (lane & 3) * 8;
      g2l16(B + (size_t)m * K + k0 + ko, sB + seg * 512);
    }
#pragma unroll
    for (int i = 0; i < 2; ++i) {
      int seg = wv + 4 * i;
      int m = seg * 16 + (lane >> 2);
      int ko = (lane & 3) * 8;
      g2l16(A + (size_t)m * K + k0 + ko, sA + seg * 512);
    }
    __syncthreads();
    s16x8 afr[4], bfr[4];
#pragma unroll
    for (int i = 0; i < 4; ++i)
      afr[i] = *(const s16x8*)(sA + (wm * 64 + i * 16 + cix) * 32 + q * 8);
#pragma unroll
    for (int i = 0; i < 4; ++i)
      bfr[i] = *(const s16x8*)(sB + (wn * 64 + i * 16 + cix) * 32 + q * 8);
#pragma unroll
    for (int i = 0; i < 4; ++i)
#pragma unroll
      for (int j = 0; j < 4; ++j)
        acc[i][j] = __builtin_amdgcn_mfma_f32_16x16x32_bf16(afr[i], bfr[j],
                                                            acc[i][j], 0, 0, 0);
  }
}

// ---------------------------------------------------------------------------
// k_cvt: convert wql|wkl|wvl|wol (each 8M fp32) -> Wb bf16.
// ---------------------------------------------------------------------------
__global__ void __launch_bounds__(256) k_cvt(
    const float* __restrict__ w0, const float* __restrict__ w1,
    const float* __restrict__ w2, const float* __restrict__ w3,
    short* __restrict__ Wb) {
  size_t i = (size_t)blockIdx.x * 256 + threadIdx.x;  // vec4 index
#pragma unroll
  for (int r = 0; r < 4; ++r) {
    const float* s = (r == 0) ? w0 : (r == 1) ? w1 : (r == 2) ? w2 : w3;
    size_t v = i + (size_t)r * 2097152;
    float4 f = *(const float4*)(s + (i << 2));
    short4 o;
    o.x = f2bf(f.x); o.y = f2bf(f.y); o.z = f2bf(f.z); o.w = f2bf(f.w);
    *(short4*)(Wb + (v << 2)) = o;
  }
}

// ---------------------------------------------------------------------------
// k_conv: fused 3x3 convs, PROJ-SERIALIZED (32 live accumulators, not 96 ->
// keeps accs in real VGPRs, no v_accvgpr ping-pong). Writes Yt[proj][c][col][h].
// ---------------------------------------------------------------------------
__global__ void __launch_bounds__(256) k_conv(
    const float* __restrict__ x,
    const float* __restrict__ wqc, const float* __restrict__ bqc,
    const float* __restrict__ wkc, const float* __restrict__ bkc,
    const float* __restrict__ wvc, const float* __restrict__ bvc,
    short* __restrict__ Yt) {
  __shared__ float xs[8][66][19];
  const int h0 = blockIdx.x * 64, w0 = blockIdx.y * 16, b = blockIdx.z;
  const int tid = threadIdx.x;
  for (int idx = tid; idx < 8 * 66 * 18; idx += 256) {
    int c = idx / (66 * 18);
    int rem = idx % (66 * 18);
    int r = rem / 18, cc = rem % 18;
    int h = h0 + r - 1, w = w0 + cc - 1;
    float v = 0.f;
    if (h >= 0 && h < 1024 && w >= 0 && w < 512)
      v = x[(((size_t)b * 8 + c) << 10 | (unsigned)h) * 512 + w];
    xs[c][r][cc] = v;
  }
  __syncthreads();
  const int hh = tid & 63;
  const int wv4 = tid >> 6;
  const size_t hgl = h0 + hh;
  for (int proj = 0; proj < 3; ++proj) {
    const float* wc = (proj == 0) ? wqc : ((proj == 1) ? wkc : wvc);
    const float* bc = (proj == 0) ? bqc : ((proj == 1) ? bkc : bvc);
    float a[4][8];
#pragma unroll
    for (int jj = 0; jj < 4; ++jj)
#pragma unroll
      for (int co = 0; co < 8; ++co) a[jj][co] = bc[co];
    for (int ci = 0; ci < 8; ++ci)
#pragma unroll
      for (int dh = 0; dh < 3; ++dh)
#pragma unroll
        for (int dw = 0; dw < 3; ++dw) {
          float xv[4];
#pragma unroll
          for (int jj = 0; jj < 4; ++jj)
            xv[jj] = xs[ci][hh + dh][wv4 * 4 + jj + dw];
          const int wi = ci * 9 + dh * 3 + dw;
#pragma unroll
          for (int co = 0; co < 8; ++co) {
            float wgt = wc[co * 72 + wi];
#pragma unroll
            for (int jj = 0; jj < 4; ++jj) a[jj][co] = fmaf(xv[jj], wgt, a[jj][co]);
          }
        }
#pragma unroll
    for (int jj = 0; jj < 4; ++jj) {
      size_t col = (size_t)b * 512 + w0 + wv4 * 4 + jj;
#pragma unroll
      for (int co = 0; co < 8; ++co)
        Yt[((size_t)(proj * 8 + co) << 20) + (col << 10) + hgl] = f2bf(a[jj][co]);
    }
  }
}

// ---------------------------------------------------------------------------
// k_qkv: 24 batched 1024^3 GEMMs, XCD-clustered 1-D grid. Epilogue: RoPE for
// q/k -> Qr/Kr[c][head][b][wpos][d]; V -> Vt[c][head][b][d][wpos] (bf16).
// ---------------------------------------------------------------------------
__global__ void __launch_bounds__(256) k_qkv(
    const short* __restrict__ Wb, const short* __restrict__ Yt,
    short* __restrict__ Qr, short* __restrict__ Kr, short* __restrict__ Vt) {
  __shared__ short sA[128 * 32], sB[128 * 32];
  const int L = blockIdx.x;
  const int lin = (L & 7) * 192 + (L >> 3);
  const int g = lin >> 6;  // 0..23 = proj*8+c
  const int t = lin & 63;
  const int proj = g >> 3, cq = g & 7;
  const int mt = t >> 3, nt = t & 7;
  const short* A = Wb + ((size_t)g << 20) + ((size_t)mt << 17);
  const short* B = Yt + ((size_t)g << 20) + ((size_t)nt << 17);
  const f32x4 fzero = {0.f, 0.f, 0.f, 0.f};
  f32x4 acc[4][4];
#pragma unroll
  for (int i = 0; i < 4; ++i)
#pragma unroll
    for (int j = 0; j < 4; ++j) acc[i][j] = fzero;
  gemm_core(A, B, 1024, sA, sB, acc);

  const int lane = threadIdx.x & 63, wv = threadIdx.x >> 6;
  const int wm = wv >> 1, wn = wv & 1, q = lane >> 4, cix = lane & 15;
  const int head = mt;
  if (proj == 2) {
#pragma unroll
    for (int mi = 0; mi < 4; ++mi) {
      int rbase = wm * 64 + mi * 16 + q * 4;  // d
#pragma unroll
      for (int ni = 0; ni < 4; ++ni) {
        int col = nt * 128 + wn * 64 + ni * 16 + cix;
        int b = col >> 9, wpos = col & 511;
        size_t base = ((size_t)((cq * 8 + head) * 2 + b) << 16) +
                      ((size_t)rbase << 9) + wpos;
        f32x4 v = acc[mi][ni];
        Vt[base] = f2bf(v[0]);
        Vt[base + 512] = f2bf(v[1]);
        Vt[base + 1024] = f2bf(v[2]);
        Vt[base + 1536] = f2bf(v[3]);
      }
    }
  } else {
    short* QKp = proj ? Kr : Qr;
#pragma unroll
    for (int mi = 0; mi < 4; ++mi) {
      int rbase = wm * 64 + mi * 16 + q * 4;  // d (even)
      int j0 = rbase >> 1;
      float if0 = exp2f(-0.20762050593046f * (float)j0);  // 10000^(-j/64)
      float if1 = exp2f(-0.20762050593046f * (float)(j0 + 1));
#pragma unroll
      for (int ni = 0; ni < 4; ++ni) {
        int col = nt * 128 + wn * 64 + ni * 16 + cix;
        int b = col >> 9, wpos = col & 511;
        float fw = (float)wpos;
        float s0, c0, s1, c1;
        __sincosf(fw * if0, &s0, &c0);
        __sincosf(fw * if1, &s1, &c1);
        f32x4 v = acc[mi][ni];
        short4 pk;
        pk.x = f2bf(v[0] * c0 - v[1] * s0);
        pk.y = f2bf(v[1] * c0 + v[0] * s0);
        pk.z = f2bf(v[2] * c1 - v[3] * s1);
        pk.w = f2bf(v[3] * c1 + v[2] * s1);
        *(short4*)&QKp[((size_t)(((cq * 8 + head) * 2 + b) * 512 + wpos) << 7) +
                       rbase] = pk;
      }
    }
  }
}

// ---------------------------------------------------------------------------
// k_attn (R2): occupancy-first. grid 1-D 512, bijective XCD swizzle so the
// 4 qt blocks of one bcn share an XCD (K/V reuse L3->L2).
//   - Q/K/V frags read DIRECT from global (all L2-resident per block/XCD);
//     no GEMM-style LDS staging at all -> LDS = Pt + psum = 35.8 KB.
//   - prev_qk pipelined in 8-float double-buffered chunks (16 VGPR).
//   - single live B-frag inside MFMA loops (VGPR peak down).
//   - __launch_bounds__(256,3): 3 blocks/CU target.
//   - setprio(1) around MFMA clusters (free-running waves -> T5 regime).
// ---------------------------------------------------------------------------
__global__ void __launch_bounds__(256, 3) k_attn(
    const short* __restrict__ Qr, const short* __restrict__ Kr,
    const short* __restrict__ Vt, const float* __restrict__ prevqk,
    float* __restrict__ qk, short* __restrict__ At) {
  __shared__ short Pt[128 * 136];   // P staging (34.8 KB)
  __shared__ float psum[128][2];
  const int tid = threadIdx.x, lane = tid & 63, wv = tid >> 6;
  const int wm = wv >> 1, wn = wv & 1, q = lane >> 4, cix = lane & 15;
  const int bid = blockIdx.x;
  const int lin = (bid & 7) * 64 + (bid >> 3);  // 512 = 8*64, bijective
  const int bcn = lin >> 2, qt = lin & 3;       // 4 qt of a bcn adjacent
  const int b = bcn >> 6, cch = (bcn >> 3) & 7, nh = bcn & 7;
  const size_t qrb = ((size_t)((cch * 8 + nh) * 2 + b)) << 16;
  const size_t rowg0 = (size_t)bcn * 512 + qt * 128;
  const int arow = wm * 64;
  const short* Qbase = Qr + qrb + ((size_t)qt << 14);

  const f32x4 fzero = {0.f, 0.f, 0.f, 0.f};
  f32x4 accO[4][4];
  float lsum[4][4];
#pragma unroll
  for (int i = 0; i < 4; ++i)
#pragma unroll
    for (int j = 0; j < 4; ++j) { accO[i][j] = fzero; lsum[i][j] = 0.f; }

  float pvA[8], pvB[8];

#pragma unroll 1
  for (int kt = 0; kt < 4; ++kt) {
    const int colb = kt * 128 + wn * 64 + cix;
    f32x4 accS[4][4];
#pragma unroll
    for (int i = 0; i < 4; ++i)
#pragma unroll
      for (int j = 0; j < 4; ++j) accS[i][j] = fzero;

    // 8-float prev chunk loader: (mi, h) covers ni = 2h, 2h+1
    auto ld8 = [&](int mi, int h, float* dst) {
#pragma unroll
      for (int u = 0; u < 2; ++u)
#pragma unroll
        for (int r = 0; r < 4; ++r)
          dst[u * 4 + r] =
              prevqk[((rowg0 + arow + mi * 16 + q * 4 + r) << 9) +
                     colb + (2 * h + u) * 16];
    };
    auto pr8 = [&](int mi, int h, const float* pv) {
#pragma unroll
      for (int u = 0; u < 2; ++u) {
        int ni = 2 * h + u;
#pragma unroll
        for (int r = 0; r < 4; ++r) {
          float s = accS[mi][ni][r] * 0.03125f + pv[u * 4 + r];
          qk[((rowg0 + arow + mi * 16 + q * 4 + r) << 9) + colb + ni * 16] = s;
          float p = __expf(s);
          lsum[mi][r] += p;
          Pt[(arow + mi * 16 + q * 4 + r) * 136 + wn * 64 + ni * 16 + cix] =
              f2bf(p);
        }
      }
    };

    // issue prev chunk (0,0) early: lands while QK^T MFMAs run
    ld8(0, 0, pvA);

    // ---- S = Q K^T : A/B frags direct from global (L2-resident) ----
    const short* Kbase = Kr + qrb + ((size_t)kt << 14);
#pragma unroll
    for (int kk = 0; kk < 4; ++kk) {
      s16x8 afr[4];
#pragma unroll
      for (int mi = 0; mi < 4; ++mi)
        afr[mi] = *(const s16x8*)(Qbase +
            ((size_t)(arow + mi * 16 + cix) << 7) + kk * 32 + q * 8);
      __builtin_amdgcn_s_setprio(1);
#pragma unroll
      for (int ni = 0; ni < 4; ++ni) {
        s16x8 bfr = *(const s16x8*)(Kbase +
            ((size_t)(wn * 64 + ni * 16 + cix) << 7) + kk * 32 + q * 8);
#pragma unroll
        for (int mi = 0; mi < 4; ++mi)
          accS[mi][ni] = __builtin_amdgcn_mfma_f32_16x16x32_bf16(
              afr[mi], bfr, accS[mi][ni], 0, 0, 0);
      }
      __builtin_amdgcn_s_setprio(0);
    }

    // ---- epilogue: s = S/32 + prev ; qk <- s ; p = exp(s) -> Pt, lsum ----
    ld8(0, 1, pvB); pr8(0, 0, pvA);
    ld8(1, 0, pvA); pr8(0, 1, pvB);
    ld8(1, 1, pvB); pr8(1, 0, pvA);
    ld8(2, 0, pvA); pr8(1, 1, pvB);
    ld8(2, 1, pvB); pr8(2, 0, pvA);
    ld8(3, 0, pvA); pr8(2, 1, pvB);
    ld8(3, 1, pvB); pr8(3, 0, pvA);
    pr8(3, 1, pvB);

    __syncthreads();  // Pt visible to all waves

    // ---- PV: A = Pt (LDS), B = Vt (global, L2-resident) ----
#pragma unroll
    for (int s4 = 0; s4 < 4; ++s4) {
      s16x8 afr[4];
#pragma unroll
      for (int i = 0; i < 4; ++i)
        afr[i] =
            *(const s16x8*)&Pt[(arow + i * 16 + cix) * 136 + s4 * 32 + q * 8];
      __builtin_amdgcn_s_setprio(1);
#pragma unroll
      for (int j = 0; j < 4; ++j) {
        s16x8 bfr = *(const s16x8*)&Vt[qrb +
                                       ((size_t)(wn * 64 + j * 16 + cix) << 9) +
                                       kt * 128 + s4 * 32 + q * 8];
#pragma unroll
        for (int i = 0; i < 4; ++i)
          accO[i][j] = __builtin_amdgcn_mfma_f32_16x16x32_bf16(
              afr[i], bfr, accO[i][j], 0, 0, 0);
      }
      __builtin_amdgcn_s_setprio(0);
    }
    __syncthreads();  // PV reads done -> Pt reusable next kt
  }

  // combine row sums across cix lanes and the two wn waves
#pragma unroll
  for (int mi = 0; mi < 4; ++mi)
#pragma unroll
    for (int r = 0; r < 4; ++r) {
      float se = lsum[mi][r];
      se += __shfl_xor(se, 1);
      se += __shfl_xor(se, 2);
      se += __shfl_xor(se, 4);
      se += __shfl_xor(se, 8);
      if (cix == 0) psum[arow + mi * 16 + q * 4 + r][wn] = se;
    }
  __syncthreads();
  // normalize and store At[c][b*512+wq][nh*128+d]
#pragma unroll
  for (int mi = 0; mi < 4; ++mi) {
    int rl = arow + mi * 16 + q * 4;
    float iL[4];
#pragma unroll
    for (int r = 0; r < 4; ++r)
      iL[r] = 1.0f / (psum[rl + r][0] + psum[rl + r][1]);
    int wq = qt * 128 + rl;
#pragma unroll
    for (int ni = 0; ni < 4; ++ni) {
      int dl = wn * 64 + ni * 16 + cix;
      size_t ob = (((size_t)cch << 10) + b * 512 + wq) * 1024 + nh * 128 + dl;
      f32x4 v = accO[mi][ni];
      At[ob] = f2bf(v[0] * iL[0]);
      At[ob + 1024] = f2bf(v[1] * iL[1]);
      At[ob + 2048] = f2bf(v[2] * iL[2]);
      At[ob + 3072] = f2bf(v[3] * iL[3]);
    }
  }
}

// ---------------------------------------------------------------------------
// k_out: role-swapped GEMM: C'[col][f] = sum_h At[col][h]*Wo[f][h]. XCD-
// clustered 1-D grid of 512. Stores float4 along w.
// ---------------------------------------------------------------------------
__global__ void __launch_bounds__(256) k_out(
    const short* __restrict__ At, const short* __restrict__ Wob,
    float* __restrict__ outp) {
  __shared__ short sA[128 * 32], sB[128 * 32];
  const int L = blockIdx.x;
  const int lin = (L & 7) * 64 + (L >> 3);
  const int c = lin >> 6;
  const int t = lin & 63;
  const int mt = t >> 3, nt = t & 7;
  const short* A = At + ((size_t)c << 20) + ((size_t)mt << 17);
  const short* B = Wob + ((size_t)c << 20) + ((size_t)nt << 17);
  const f32x4 fzero = {0.f, 0.f, 0.f, 0.f};
  f32x4 acc[4][4];
#pragma unroll
  for (int i = 0; i < 4; ++i)
#pragma unroll
    for (int j = 0; j < 4; ++j) acc[i][j] = fzero;
  gemm_core(A, B, 1024, sA, sB, acc);

  const int lane = threadIdx.x & 63, wv = threadIdx.x >> 6;
  const int wm = wv >> 1, wn = wv & 1, q = lane >> 4, cix = lane & 15;
#pragma unroll
  for (int mi = 0; mi < 4; ++mi) {
    int colm = mt * 128 + wm * 64 + mi * 16 + q * 4;
    int b = colm >> 9, w = colm & 511;
#pragma unroll
    for (int ni = 0; ni < 4; ++ni) {
      int f = nt * 128 + wn * 64 + ni * 16 + cix;
      f32x4 v = acc[mi][ni];
      float4 st; st.x = v[0]; st.y = v[1]; st.z = v[2]; st.w = v[3];
      *(float4*)&outp[((((size_t)b * 8 + c) << 10) + f) * 512 + w] = st;
    }
  }
}

// ---------------------------------------------------------------------------
extern "C" void kernel_launch(void* const* d_in, const int* in_sizes, int n_in,
                              void* d_out, int out_size, void* d_ws,
                              size_t ws_size, hipStream_t stream) {
  const float* x = (const float*)d_in[0];
  const float* prevqk = (const float*)d_in[1];
  const float* wqc = (const float*)d_in[2];
  const float* bqc = (const float*)d_in[3];
  const float* wql = (const float*)d_in[4];
  const float* wkc = (const float*)d_in[5];
  const float* bkc = (const float*)d_in[6];
  const float* wkl = (const float*)d_in[7];
  const float* wvc = (const float*)d_in[8];
  const float* bvc = (const float*)d_in[9];
  const float* wvl = (const float*)d_in[10];
  const float* wol = (const float*)d_in[11];
  float* outp = (float*)d_out;
  float* qk = outp + 8388608;  // out is B*C*F*W floats, then qk

  char* ws = (char*)d_ws;
  short* Wb = (short*)ws;                  // 67,108,864 B (4 weight mats bf16)
  short* Yt = (short*)(ws + 67108864);     // 50,331,648 B
  short* Qr = (short*)(ws + 117440512);    // 16,777,216 B
  short* Kr = (short*)(ws + 134217728);    // 16,777,216 B
  short* Vt = (short*)(ws + 150994944);    // 16,777,216 B
  short* At = (short*)(ws + 67108864);     // alias Yt (dead after k_qkv)
  short* Wob = Wb + ((size_t)24 << 20);    // wo segment of Wb

  k_cvt<<<dim3(8192), 256, 0, stream>>>(wql, wkl, wvl, wol, Wb);
  k_conv<<<dim3(16, 32, 2), 256, 0, stream>>>(x, wqc, bqc, wkc, bkc, wvc, bvc, Yt);
  k_qkv<<<dim3(1536), 256, 0, stream>>>(Wb, Yt, Qr, Kr, Vt);
  k_attn<<<dim3(512), 256, 0, stream>>>(Qr, Kr, Vt, prevqk, qk, At);
  k_out<<<dim3(512), 256, 0, stream>>>(At, Wob, outp);
}

// Round 3
// 584.621 us; speedup vs baseline: 1.1470x; 1.1470x over previous
//
#include <hip/hip_runtime.h>
#include <stdint.h>

// ---------------------------------------------------------------------------
// MultichannelMultiheadAttention: B=2,C=8,F=1024,W=512,NH=8,HD=128
// cvt(W_lin->bf16) ; conv3x3(q,k,v, proj-serialized) -> per-channel linear
// (bf16 MFMA GEMM) -> RoPE -> fused flash-style attention (S=QK^T/32+prev,
// qk written, softmax WITHOUT max-subtraction [|scores|<1 by construction],
// PV accumulate) -> out linear.
// R3: k_attn = R1 structure restored (R2's launch_bounds(256,3) spilled the
// 128-VGPR accumulator arrays to scratch: VGPR 184->84, +160MB scratch
// writes, 2x time). Kept from R2: bijective XCD-grouped 1-D grid (4 qt of a
// bcn share an XCD's L2) + setprio around MFMA clusters. launch_bounds(256,2).
// ---------------------------------------------------------------------------

typedef float f32x4 __attribute__((ext_vector_type(4)));
typedef short s16x8 __attribute__((ext_vector_type(8)));

__device__ __forceinline__ short f2bf(float f) {
  union { float f; uint32_t u; } v; v.f = f;
  uint32_t r = v.u + 0x7FFFu + ((v.u >> 16) & 1u);  // RNE
  return (short)(r >> 16);
}

__device__ __forceinline__ void g2l16(const void* g, void* l) {
  __builtin_amdgcn_global_load_lds(
      (const __attribute__((address_space(1))) void*)g,
      (__attribute__((address_space(3))) void*)l, 16, 0, 0);
}

// ---------------------------------------------------------------------------
// GEMM core: C[128x128] = A(128xK) * B^T, B stored (128 x K), both bf16
// row-major K-contiguous. 256 thr, 2x2 waves, 4x4 frags of 16x16x32.
// (used by k_qkv / k_out)
// ---------------------------------------------------------------------------
__device__ __forceinline__ void gemm_core(const short* __restrict__ A,
                                          const short* __restrict__ B,
                                          int K, short* sA, short* sB,
                                          f32x4 (*acc)[4]) {
  const int tid = threadIdx.x;
  const int lane = tid & 63;
  const int wv = tid >> 6;
  const int wm = wv >> 1, wn = wv & 1;
  const int q = lane >> 4, cix = lane & 15;

  for (int k0 = 0; k0 < K; k0 += 32) {
    __syncthreads();
#pragma unroll
    for (int i = 0; i < 2; ++i) {
      int seg = wv + 4 * i;  // wave-uniform LDS base
      int m = seg * 16 + (lane >> 2);
      int ko = (lane & 3) * 8;
      g2l16(B + (size_t)m * K + k0 + ko, sB + seg * 512);
    }
#pragma unroll
    for (int i = 0; i < 2; ++i) {
      int seg = wv + 4 * i;
      int m = seg * 16 + (lane >> 2);
      int ko = (lane & 3) * 8;
      g2l16(A + (size_t)m * K + k0 + ko, sA + seg * 512);
    }
    __syncthreads();
    s16x8 afr[4], bfr[4];
#pragma unroll
    for (int i = 0; i < 4; ++i)
      afr[i] = *(const s16x8*)(sA + (wm * 64 + i * 16 + cix) * 32 + q * 8);
#pragma unroll
    for (int i = 0; i < 4; ++i)
      bfr[i] = *(const s16x8*)(sB + (wn * 64 + i * 16 + cix) * 32 + q * 8);
#pragma unroll
    for (int i = 0; i < 4; ++i)
#pragma unroll
      for (int j = 0; j < 4; ++j)
        acc[i][j] = __builtin_amdgcn_mfma_f32_16x16x32_bf16(afr[i], bfr[j],
                                                            acc[i][j], 0, 0, 0);
  }
}

// ---------------------------------------------------------------------------
// k_cvt: convert wql|wkl|wvl|wol (each 8M fp32) -> Wb bf16.
// ---------------------------------------------------------------------------
__global__ void __launch_bounds__(256) k_cvt(
    const float* __restrict__ w0, const float* __restrict__ w1,
    const float* __restrict__ w2, const float* __restrict__ w3,
    short* __restrict__ Wb) {
  size_t i = (size_t)blockIdx.x * 256 + threadIdx.x;  // vec4 index
#pragma unroll
  for (int r = 0; r < 4; ++r) {
    const float* s = (r == 0) ? w0 : (r == 1) ? w1 : (r == 2) ? w2 : w3;
    size_t v = i + (size_t)r * 2097152;
    float4 f = *(const float4*)(s + (i << 2));
    short4 o;
    o.x = f2bf(f.x); o.y = f2bf(f.y); o.z = f2bf(f.z); o.w = f2bf(f.w);
    *(short4*)(Wb + (v << 2)) = o;
  }
}

// ---------------------------------------------------------------------------
// k_conv: fused 3x3 convs, PROJ-SERIALIZED (32 live accumulators, not 96 ->
// keeps accs in real VGPRs, no v_accvgpr ping-pong). Writes Yt[proj][c][col][h].
// ---------------------------------------------------------------------------
__global__ void __launch_bounds__(256) k_conv(
    const float* __restrict__ x,
    const float* __restrict__ wqc, const float* __restrict__ bqc,
    const float* __restrict__ wkc, const float* __restrict__ bkc,
    const float* __restrict__ wvc, const float* __restrict__ bvc,
    short* __restrict__ Yt) {
  __shared__ float xs[8][66][19];
  const int h0 = blockIdx.x * 64, w0 = blockIdx.y * 16, b = blockIdx.z;
  const int tid = threadIdx.x;
  for (int idx = tid; idx < 8 * 66 * 18; idx += 256) {
    int c = idx / (66 * 18);
    int rem = idx % (66 * 18);
    int r = rem / 18, cc = rem % 18;
    int h = h0 + r - 1, w = w0 + cc - 1;
    float v = 0.f;
    if (h >= 0 && h < 1024 && w >= 0 && w < 512)
      v = x[(((size_t)b * 8 + c) << 10 | (unsigned)h) * 512 + w];
    xs[c][r][cc] = v;
  }
  __syncthreads();
  const int hh = tid & 63;
  const int wv4 = tid >> 6;
  const size_t hgl = h0 + hh;
  for (int proj = 0; proj < 3; ++proj) {
    const float* wc = (proj == 0) ? wqc : ((proj == 1) ? wkc : wvc);
    const float* bc = (proj == 0) ? bqc : ((proj == 1) ? bkc : bvc);
    float a[4][8];
#pragma unroll
    for (int jj = 0; jj < 4; ++jj)
#pragma unroll
      for (int co = 0; co < 8; ++co) a[jj][co] = bc[co];
    for (int ci = 0; ci < 8; ++ci)
#pragma unroll
      for (int dh = 0; dh < 3; ++dh)
#pragma unroll
        for (int dw = 0; dw < 3; ++dw) {
          float xv[4];
#pragma unroll
          for (int jj = 0; jj < 4; ++jj)
            xv[jj] = xs[ci][hh + dh][wv4 * 4 + jj + dw];
          const int wi = ci * 9 + dh * 3 + dw;
#pragma unroll
          for (int co = 0; co < 8; ++co) {
            float wgt = wc[co * 72 + wi];
#pragma unroll
            for (int jj = 0; jj < 4; ++jj) a[jj][co] = fmaf(xv[jj], wgt, a[jj][co]);
          }
        }
#pragma unroll
    for (int jj = 0; jj < 4; ++jj) {
      size_t col = (size_t)b * 512 + w0 + wv4 * 4 + jj;
#pragma unroll
      for (int co = 0; co < 8; ++co)
        Yt[((size_t)(proj * 8 + co) << 20) + (col << 10) + hgl] = f2bf(a[jj][co]);
    }
  }
}

// ---------------------------------------------------------------------------
// k_qkv: 24 batched 1024^3 GEMMs, XCD-clustered 1-D grid. Epilogue: RoPE for
// q/k -> Qr/Kr[c][head][b][wpos][d]; V -> Vt[c][head][b][d][wpos] (bf16).
// ---------------------------------------------------------------------------
__global__ void __launch_bounds__(256) k_qkv(
    const short* __restrict__ Wb, const short* __restrict__ Yt,
    short* __restrict__ Qr, short* __restrict__ Kr, short* __restrict__ Vt) {
  __shared__ short sA[128 * 32], sB[128 * 32];
  const int L = blockIdx.x;
  const int lin = (L & 7) * 192 + (L >> 3);
  const int g = lin >> 6;  // 0..23 = proj*8+c
  const int t = lin & 63;
  const int proj = g >> 3, cq = g & 7;
  const int mt = t >> 3, nt = t & 7;
  const short* A = Wb + ((size_t)g << 20) + ((size_t)mt << 17);
  const short* B = Yt + ((size_t)g << 20) + ((size_t)nt << 17);
  const f32x4 fzero = {0.f, 0.f, 0.f, 0.f};
  f32x4 acc[4][4];
#pragma unroll
  for (int i = 0; i < 4; ++i)
#pragma unroll
    for (int j = 0; j < 4; ++j) acc[i][j] = fzero;
  gemm_core(A, B, 1024, sA, sB, acc);

  const int lane = threadIdx.x & 63, wv = threadIdx.x >> 6;
  const int wm = wv >> 1, wn = wv & 1, q = lane >> 4, cix = lane & 15;
  const int head = mt;
  if (proj == 2) {
#pragma unroll
    for (int mi = 0; mi < 4; ++mi) {
      int rbase = wm * 64 + mi * 16 + q * 4;  // d
#pragma unroll
      for (int ni = 0; ni < 4; ++ni) {
        int col = nt * 128 + wn * 64 + ni * 16 + cix;
        int b = col >> 9, wpos = col & 511;
        size_t base = ((size_t)((cq * 8 + head) * 2 + b) << 16) +
                      ((size_t)rbase << 9) + wpos;
        f32x4 v = acc[mi][ni];
        Vt[base] = f2bf(v[0]);
        Vt[base + 512] = f2bf(v[1]);
        Vt[base + 1024] = f2bf(v[2]);
        Vt[base + 1536] = f2bf(v[3]);
      }
    }
  } else {
    short* QKp = proj ? Kr : Qr;
#pragma unroll
    for (int mi = 0; mi < 4; ++mi) {
      int rbase = wm * 64 + mi * 16 + q * 4;  // d (even)
      int j0 = rbase >> 1;
      float if0 = exp2f(-0.20762050593046f * (float)j0);  // 10000^(-j/64)
      float if1 = exp2f(-0.20762050593046f * (float)(j0 + 1));
#pragma unroll
      for (int ni = 0; ni < 4; ++ni) {
        int col = nt * 128 + wn * 64 + ni * 16 + cix;
        int b = col >> 9, wpos = col & 511;
        float fw = (float)wpos;
        float s0, c0, s1, c1;
        __sincosf(fw * if0, &s0, &c0);
        __sincosf(fw * if1, &s1, &c1);
        f32x4 v = acc[mi][ni];
        short4 pk;
        pk.x = f2bf(v[0] * c0 - v[1] * s0);
        pk.y = f2bf(v[1] * c0 + v[0] * s0);
        pk.z = f2bf(v[2] * c1 - v[3] * s1);
        pk.w = f2bf(v[3] * c1 + v[2] * s1);
        *(short4*)&QKp[((size_t)(((cq * 8 + head) * 2 + b) * 512 + wpos) << 7) +
                       rbase] = pk;
      }
    }
  }
}

// ---------------------------------------------------------------------------
// k_attn (R3 = R1 structure): fused S=QK^T/32+prev (qk written) -> softmax
// (no max subtraction) -> PV -> At. 1-D grid 512, bijective XCD swizzle so
// the 4 qt blocks of one bcn share an XCD (K/V reuse in that XCD's L2).
//   - Q tile (32 KB) staged to LDS ONCE via global_load_lds with
//     inverse-swizzled SOURCE (linear dest); frag reads XOR-swizzled
//     (byte ^= (row&15)<<4) -> conflict-free ds_read_b128.
//   - K frags direct from global (L2-resident): QK^T phase has NO barriers.
//   - prev_qk double-buffered in 16-float chunks; chunk 0 issued before the
//     MFMA cluster so HBM latency hides under QK^T.
//   - setprio(1) around MFMA clusters (free-running waves -> T5 regime).
//   - launch_bounds(256,2): accumulators (128 VGPR) MUST stay in registers;
//     (256,3) spilled them to scratch (R2: VGPR 84, +160MB writes, 2x time).
// ---------------------------------------------------------------------------
__global__ void __launch_bounds__(256, 2) k_attn(
    const short* __restrict__ Qr, const short* __restrict__ Kr,
    const short* __restrict__ Vt, const float* __restrict__ prevqk,
    float* __restrict__ qk, short* __restrict__ At) {
  __shared__ short Qs[128 * 128];   // swizzled Q tile (32 KB)
  __shared__ short Pt[128 * 136];   // P staging (34.8 KB)
  __shared__ float psum[128][2];
  const int tid = threadIdx.x, lane = tid & 63, wv = tid >> 6;
  const int wm = wv >> 1, wn = wv & 1, q = lane >> 4, cix = lane & 15;
  const int bid = blockIdx.x;
  const int lin = (bid & 7) * 64 + (bid >> 3);  // 512 = 8*64, bijective
  const int bcn = lin >> 2, qt = lin & 3;       // 4 qt of a bcn adjacent
  const int b = bcn >> 6, cch = (bcn >> 3) & 7, nh = bcn & 7;
  const size_t qrb = ((size_t)((cch * 8 + nh) * 2 + b)) << 16;
  const size_t rowg0 = (size_t)bcn * 512 + qt * 128;
  const int arow = wm * 64;

  // ---- stage Q once: linear LDS dest, inverse-swizzled global source ----
  {
    const char* Qg = (const char*)(Qr + qrb + ((size_t)qt << 14));
#pragma unroll
    for (int i = 0; i < 8; ++i) {
      int Lb = i * 4096 + wv * 1024;           // wave-uniform dest byte
      int L = Lb + (lane << 4);                // this lane's dest byte
      int src = (L & ~255) | ((L & 255) ^ (((L >> 8) & 15) << 4));
      g2l16(Qg + src, (char*)Qs + Lb);
    }
  }
  __syncthreads();

  const f32x4 fzero = {0.f, 0.f, 0.f, 0.f};
  f32x4 accO[4][4];
  float lsum[4][4];
#pragma unroll
  for (int i = 0; i < 4; ++i)
#pragma unroll
    for (int j = 0; j < 4; ++j) { accO[i][j] = fzero; lsum[i][j] = 0.f; }

  float pvA[16], pvB[16];

#pragma unroll 1
  for (int kt = 0; kt < 4; ++kt) {
    const int colb = kt * 128 + wn * 64 + cix;
    f32x4 accS[4][4];
#pragma unroll
    for (int i = 0; i < 4; ++i)
#pragma unroll
      for (int j = 0; j < 4; ++j) accS[i][j] = fzero;

    // issue prev chunk 0 early: lands while QK^T MFMAs run
#pragma unroll
    for (int ni = 0; ni < 4; ++ni)
#pragma unroll
      for (int r = 0; r < 4; ++r)
        pvA[ni * 4 + r] =
            prevqk[((rowg0 + arow + q * 4 + r) << 9) + colb + ni * 16];

    // ---- S = Q K^T : A-frags from swizzled LDS, B-frags direct global ----
    const short* Kbase = Kr + qrb + ((size_t)kt << 14);
#pragma unroll
    for (int kk = 0; kk < 4; ++kk) {
      s16x8 afr[4], bfr[4];
      const int cb = kk * 64 + q * 16;  // byte col within Q row
#pragma unroll
      for (int ni = 0; ni < 4; ++ni)
        bfr[ni] = *(const s16x8*)(Kbase +
            ((size_t)(wn * 64 + ni * 16 + cix) << 7) + kk * 32 + q * 8);
#pragma unroll
      for (int mi = 0; mi < 4; ++mi) {
        const int row = arow + mi * 16 + cix;
        afr[mi] = *(const s16x8*)((const char*)Qs + row * 256 +
                                  (cb ^ ((row & 15) << 4)));
      }
      __builtin_amdgcn_s_setprio(1);
#pragma unroll
      for (int mi = 0; mi < 4; ++mi)
#pragma unroll
        for (int ni = 0; ni < 4; ++ni)
          accS[mi][ni] = __builtin_amdgcn_mfma_f32_16x16x32_bf16(
              afr[mi], bfr[ni], accS[mi][ni], 0, 0, 0);
      __builtin_amdgcn_s_setprio(0);
    }

    // ---- epilogue: s = S/32 + prev ; qk <- s ; p = exp(s) -> Pt, lsum ----
    auto ldchunk = [&](int mi, float* dst) {
#pragma unroll
      for (int ni = 0; ni < 4; ++ni)
#pragma unroll
        for (int r = 0; r < 4; ++r)
          dst[ni * 4 + r] =
              prevqk[((rowg0 + arow + mi * 16 + q * 4 + r) << 9) +
                     colb + ni * 16];
    };
    auto process = [&](int mi, const float* pv) {
      float rs[4] = {0.f, 0.f, 0.f, 0.f};
#pragma unroll
      for (int ni = 0; ni < 4; ++ni)
#pragma unroll
        for (int r = 0; r < 4; ++r) {
          float s = accS[mi][ni][r] * 0.03125f + pv[ni * 4 + r];
          qk[((rowg0 + arow + mi * 16 + q * 4 + r) << 9) + colb + ni * 16] = s;
          float p = __expf(s);
          rs[r] += p;
          Pt[(arow + mi * 16 + q * 4 + r) * 136 + wn * 64 + ni * 16 + cix] =
              f2bf(p);
        }
#pragma unroll
      for (int r = 0; r < 4; ++r) lsum[mi][r] += rs[r];
    };
    ldchunk(1, pvB);
    process(0, pvA);
    ldchunk(2, pvA);
    process(1, pvB);
    ldchunk(3, pvB);
    process(2, pvA);
    process(3, pvB);

    __syncthreads();  // Pt visible to all waves

    // ---- PV: A = Pt (LDS), B = Vt (global, L2-resident) ----
#pragma unroll
    for (int s4 = 0; s4 < 4; ++s4) {
      s16x8 afr[4], bfr[4];
#pragma unroll
      for (int i = 0; i < 4; ++i)
        afr[i] =
            *(const s16x8*)&Pt[(arow + i * 16 + cix) * 136 + s4 * 32 + q * 8];
#pragma unroll
      for (int i = 0; i < 4; ++i)
        bfr[i] = *(const s16x8*)&Vt[qrb +
                                    ((size_t)(wn * 64 + i * 16 + cix) << 9) +
                                    kt * 128 + s4 * 32 + q * 8];
      __builtin_amdgcn_s_setprio(1);
#pragma unroll
      for (int i = 0; i < 4; ++i)
#pragma unroll
        for (int j = 0; j < 4; ++j)
          accO[i][j] = __builtin_amdgcn_mfma_f32_16x16x32_bf16(
              afr[i], bfr[j], accO[i][j], 0, 0, 0);
      __builtin_amdgcn_s_setprio(0);
    }
    __syncthreads();  // PV reads done -> Pt reusable next kt
  }

  // combine row sums across cix lanes and the two wn waves
#pragma unroll
  for (int mi = 0; mi < 4; ++mi)
#pragma unroll
    for (int r = 0; r < 4; ++r) {
      float se = lsum[mi][r];
      se += __shfl_xor(se, 1);
      se += __shfl_xor(se, 2);
      se += __shfl_xor(se, 4);
      se += __shfl_xor(se, 8);
      if (cix == 0) psum[arow + mi * 16 + q * 4 + r][wn] = se;
    }
  __syncthreads();
  // normalize and store At[c][b*512+wq][nh*128+d]
#pragma unroll
  for (int mi = 0; mi < 4; ++mi) {
    int rl = arow + mi * 16 + q * 4;
    float iL[4];
#pragma unroll
    for (int r = 0; r < 4; ++r)
      iL[r] = 1.0f / (psum[rl + r][0] + psum[rl + r][1]);
    int wq = qt * 128 + rl;
#pragma unroll
    for (int ni = 0; ni < 4; ++ni) {
      int dl = wn * 64 + ni * 16 + cix;
      size_t ob = (((size_t)cch << 10) + b * 512 + wq) * 1024 + nh * 128 + dl;
      f32x4 v = accO[mi][ni];
      At[ob] = f2bf(v[0] * iL[0]);
      At[ob + 1024] = f2bf(v[1] * iL[1]);
      At[ob + 2048] = f2bf(v[2] * iL[2]);
      At[ob + 3072] = f2bf(v[3] * iL[3]);
    }
  }
}

// ---------------------------------------------------------------------------
// k_out: role-swapped GEMM: C'[col][f] = sum_h At[col][h]*Wo[f][h]. XCD-
// clustered 1-D grid of 512. Stores float4 along w.
// ---------------------------------------------------------------------------
__global__ void __launch_bounds__(256) k_out(
    const short* __restrict__ At, const short* __restrict__ Wob,
    float* __restrict__ outp) {
  __shared__ short sA[128 * 32], sB[128 * 32];
  const int L = blockIdx.x;
  const int lin = (L & 7) * 64 + (L >> 3);
  const int c = lin >> 6;
  const int t = lin & 63;
  const int mt = t >> 3, nt = t & 7;
  const short* A = At + ((size_t)c << 20) + ((size_t)mt << 17);
  const short* B = Wob + ((size_t)c << 20) + ((size_t)nt << 17);
  const f32x4 fzero = {0.f, 0.f, 0.f, 0.f};
  f32x4 acc[4][4];
#pragma unroll
  for (int i = 0; i < 4; ++i)
#pragma unroll
    for (int j = 0; j < 4; ++j) acc[i][j] = fzero;
  gemm_core(A, B, 1024, sA, sB, acc);

  const int lane = threadIdx.x & 63, wv = threadIdx.x >> 6;
  const int wm = wv >> 1, wn = wv & 1, q = lane >> 4, cix = lane & 15;
#pragma unroll
  for (int mi = 0; mi < 4; ++mi) {
    int colm = mt * 128 + wm * 64 + mi * 16 + q * 4;
    int b = colm >> 9, w = colm & 511;
#pragma unroll
    for (int ni = 0; ni < 4; ++ni) {
      int f = nt * 128 + wn * 64 + ni * 16 + cix;
      f32x4 v = acc[mi][ni];
      float4 st; st.x = v[0]; st.y = v[1]; st.z = v[2]; st.w = v[3];
      *(float4*)&outp[((((size_t)b * 8 + c) << 10) + f) * 512 + w] = st;
    }
  }
}

// ---------------------------------------------------------------------------
extern "C" void kernel_launch(void* const* d_in, const int* in_sizes, int n_in,
                              void* d_out, int out_size, void* d_ws,
                              size_t ws_size, hipStream_t stream) {
  const float* x = (const float*)d_in[0];
  const float* prevqk = (const float*)d_in[1];
  const float* wqc = (const float*)d_in[2];
  const float* bqc = (const float*)d_in[3];
  const float* wql = (const float*)d_in[4];
  const float* wkc = (const float*)d_in[5];
  const float* bkc = (const float*)d_in[6];
  const float* wkl = (const float*)d_in[7];
  const float* wvc = (const float*)d_in[8];
  const float* bvc = (const float*)d_in[9];
  const float* wvl = (const float*)d_in[10];
  const float* wol = (const float*)d_in[11];
  float* outp = (float*)d_out;
  float* qk = outp + 8388608;  // out is B*C*F*W floats, then qk

  char* ws = (char*)d_ws;
  short* Wb = (short*)ws;                  // 67,108,864 B (4 weight mats bf16)
  short* Yt = (short*)(ws + 67108864);     // 50,331,648 B
  short* Qr = (short*)(ws + 117440512);    // 16,777,216 B
  short* Kr = (short*)(ws + 134217728);    // 16,777,216 B
  short* Vt = (short*)(ws + 150994944);    // 16,777,216 B
  short* At = (short*)(ws + 67108864);     // alias Yt (dead after k_qkv)
  short* Wob = Wb + ((size_t)24 << 20);    // wo segment of Wb

  k_cvt<<<dim3(8192), 256, 0, stream>>>(wql, wkl, wvl, wol, Wb);
  k_conv<<<dim3(16, 32, 2), 256, 0, stream>>>(x, wqc, bqc, wkc, bkc, wvc, bvc, Yt);
  k_qkv<<<dim3(1536), 256, 0, stream>>>(Wb, Yt, Qr, Kr, Vt);
  k_attn<<<dim3(512), 256, 0, stream>>>(Qr, Kr, Vt, prevqk, qk, At);
  k_out<<<dim3(512), 256, 0, stream>>>(At, Wob, outp);
}

// Round 4
// 578.235 us; speedup vs baseline: 1.1597x; 1.0110x over previous
//
#include <hip/hip_runtime.h>
#include <stdint.h>

// ---------------------------------------------------------------------------
// MultichannelMultiheadAttention: B=2,C=8,F=1024,W=512,NH=8,HD=128
// cvt(W_lin->bf16) ; conv3x3(q,k,v, proj-serialized) -> per-channel linear
// (bf16 MFMA GEMM) -> RoPE -> fused flash-style attention (S=QK^T/32+prev,
// qk written, softmax WITHOUT max-subtraction [|scores|<1 by construction],
// PV accumulate) -> out linear.
// R4: gemm_core rewritten as double-buffered PREFETCH loop (T3-lite): next
// tile's global_load_lds issued BEFORE compute on current tile, single
// barrier per K-step (was: issue -> immediate vmcnt(0) drain -> compute,
// fully serial latency). Applies to k_qkv + k_out. k_attn = R3 (known-good).
// ---------------------------------------------------------------------------

typedef float f32x4 __attribute__((ext_vector_type(4)));
typedef short s16x8 __attribute__((ext_vector_type(8)));

__device__ __forceinline__ short f2bf(float f) {
  union { float f; uint32_t u; } v; v.f = f;
  uint32_t r = v.u + 0x7FFFu + ((v.u >> 16) & 1u);  // RNE
  return (short)(r >> 16);
}

__device__ __forceinline__ void g2l16(const void* g, void* l) {
  __builtin_amdgcn_global_load_lds(
      (const __attribute__((address_space(1))) void*)g,
      (__attribute__((address_space(3))) void*)l, 16, 0, 0);
}

// ---------------------------------------------------------------------------
// GEMM core: C[128x128] = A(128xK) * B^T, B stored (128 x K), both bf16
// row-major K-contiguous. 256 thr, 2x2 waves, 4x4 frags of 16x16x32.
// Double-buffered: sA/sB are 2x(128x32) each. Prefetch k+1 under compute(k);
// one barrier per K-step (its vmcnt(0)+lgkmcnt(0) drain orders both the
// prefetch completion and the LDS reads before buffer reuse).
// ---------------------------------------------------------------------------
__device__ __forceinline__ void gemm_core(const short* __restrict__ A,
                                          const short* __restrict__ B,
                                          int K, short* sA, short* sB,
                                          f32x4 (*acc)[4]) {
  const int tid = threadIdx.x;
  const int lane = tid & 63;
  const int wv = tid >> 6;
  const int wm = wv >> 1, wn = wv & 1;
  const int q = lane >> 4, cix = lane & 15;
  const int mrow = lane >> 2;
  const int ko8 = (lane & 3) * 8;

  auto stage = [&](int k0, int buf) {
    short* dA = sA + buf * 4096;
    short* dB = sB + buf * 4096;
#pragma unroll
    for (int i = 0; i < 2; ++i) {
      int seg = wv + 4 * i;  // wave-uniform LDS base
      int m = seg * 16 + mrow;
      g2l16(B + (size_t)m * K + k0 + ko8, dB + seg * 512);
    }
#pragma unroll
    for (int i = 0; i < 2; ++i) {
      int seg = wv + 4 * i;
      int m = seg * 16 + mrow;
      g2l16(A + (size_t)m * K + k0 + ko8, dA + seg * 512);
    }
  };

  stage(0, 0);
  __syncthreads();  // buf0 staged (vmcnt drain) before first compute
  int buf = 0;
  for (int k0 = 0; k0 < K; k0 += 32) {
    if (k0 + 32 < K) stage(k0 + 32, buf ^ 1);  // prefetch under compute
    const short* cA = sA + buf * 4096;
    const short* cB = sB + buf * 4096;
    s16x8 afr[4], bfr[4];
#pragma unroll
    for (int i = 0; i < 4; ++i)
      afr[i] = *(const s16x8*)(cA + (wm * 64 + i * 16 + cix) * 32 + q * 8);
#pragma unroll
    for (int i = 0; i < 4; ++i)
      bfr[i] = *(const s16x8*)(cB + (wn * 64 + i * 16 + cix) * 32 + q * 8);
#pragma unroll
    for (int i = 0; i < 4; ++i)
#pragma unroll
      for (int j = 0; j < 4; ++j)
        acc[i][j] = __builtin_amdgcn_mfma_f32_16x16x32_bf16(afr[i], bfr[j],
                                                            acc[i][j], 0, 0, 0);
    __syncthreads();  // prefetch landed + all reads of buf done -> flip
    buf ^= 1;
  }
}

// ---------------------------------------------------------------------------
// k_cvt: convert wql|wkl|wvl|wol (each 8M fp32) -> Wb bf16.
// ---------------------------------------------------------------------------
__global__ void __launch_bounds__(256) k_cvt(
    const float* __restrict__ w0, const float* __restrict__ w1,
    const float* __restrict__ w2, const float* __restrict__ w3,
    short* __restrict__ Wb) {
  size_t i = (size_t)blockIdx.x * 256 + threadIdx.x;  // vec4 index
#pragma unroll
  for (int r = 0; r < 4; ++r) {
    const float* s = (r == 0) ? w0 : (r == 1) ? w1 : (r == 2) ? w2 : w3;
    size_t v = i + (size_t)r * 2097152;
    float4 f = *(const float4*)(s + (i << 2));
    short4 o;
    o.x = f2bf(f.x); o.y = f2bf(f.y); o.z = f2bf(f.z); o.w = f2bf(f.w);
    *(short4*)(Wb + (v << 2)) = o;
  }
}

// ---------------------------------------------------------------------------
// k_conv: fused 3x3 convs, PROJ-SERIALIZED (32 live accumulators, not 96 ->
// keeps accs in real VGPRs, no v_accvgpr ping-pong). Writes Yt[proj][c][col][h].
// ---------------------------------------------------------------------------
__global__ void __launch_bounds__(256) k_conv(
    const float* __restrict__ x,
    const float* __restrict__ wqc, const float* __restrict__ bqc,
    const float* __restrict__ wkc, const float* __restrict__ bkc,
    const float* __restrict__ wvc, const float* __restrict__ bvc,
    short* __restrict__ Yt) {
  __shared__ float xs[8][66][19];
  const int h0 = blockIdx.x * 64, w0 = blockIdx.y * 16, b = blockIdx.z;
  const int tid = threadIdx.x;
  for (int idx = tid; idx < 8 * 66 * 18; idx += 256) {
    int c = idx / (66 * 18);
    int rem = idx % (66 * 18);
    int r = rem / 18, cc = rem % 18;
    int h = h0 + r - 1, w = w0 + cc - 1;
    float v = 0.f;
    if (h >= 0 && h < 1024 && w >= 0 && w < 512)
      v = x[(((size_t)b * 8 + c) << 10 | (unsigned)h) * 512 + w];
    xs[c][r][cc] = v;
  }
  __syncthreads();
  const int hh = tid & 63;
  const int wv4 = tid >> 6;
  const size_t hgl = h0 + hh;
  for (int proj = 0; proj < 3; ++proj) {
    const float* wc = (proj == 0) ? wqc : ((proj == 1) ? wkc : wvc);
    const float* bc = (proj == 0) ? bqc : ((proj == 1) ? bkc : bvc);
    float a[4][8];
#pragma unroll
    for (int jj = 0; jj < 4; ++jj)
#pragma unroll
      for (int co = 0; co < 8; ++co) a[jj][co] = bc[co];
    for (int ci = 0; ci < 8; ++ci)
#pragma unroll
      for (int dh = 0; dh < 3; ++dh)
#pragma unroll
        for (int dw = 0; dw < 3; ++dw) {
          float xv[4];
#pragma unroll
          for (int jj = 0; jj < 4; ++jj)
            xv[jj] = xs[ci][hh + dh][wv4 * 4 + jj + dw];
          const int wi = ci * 9 + dh * 3 + dw;
#pragma unroll
          for (int co = 0; co < 8; ++co) {
            float wgt = wc[co * 72 + wi];
#pragma unroll
            for (int jj = 0; jj < 4; ++jj) a[jj][co] = fmaf(xv[jj], wgt, a[jj][co]);
          }
        }
#pragma unroll
    for (int jj = 0; jj < 4; ++jj) {
      size_t col = (size_t)b * 512 + w0 + wv4 * 4 + jj;
#pragma unroll
      for (int co = 0; co < 8; ++co)
        Yt[((size_t)(proj * 8 + co) << 20) + (col << 10) + hgl] = f2bf(a[jj][co]);
    }
  }
}

// ---------------------------------------------------------------------------
// k_qkv: 24 batched 1024^3 GEMMs, XCD-clustered 1-D grid. Epilogue: RoPE for
// q/k -> Qr/Kr[c][head][b][wpos][d]; V -> Vt[c][head][b][d][wpos] (bf16).
// ---------------------------------------------------------------------------
__global__ void __launch_bounds__(256) k_qkv(
    const short* __restrict__ Wb, const short* __restrict__ Yt,
    short* __restrict__ Qr, short* __restrict__ Kr, short* __restrict__ Vt) {
  __shared__ short sA[2 * 128 * 32], sB[2 * 128 * 32];
  const int L = blockIdx.x;
  const int lin = (L & 7) * 192 + (L >> 3);
  const int g = lin >> 6;  // 0..23 = proj*8+c
  const int t = lin & 63;
  const int proj = g >> 3, cq = g & 7;
  const int mt = t >> 3, nt = t & 7;
  const short* A = Wb + ((size_t)g << 20) + ((size_t)mt << 17);
  const short* B = Yt + ((size_t)g << 20) + ((size_t)nt << 17);
  const f32x4 fzero = {0.f, 0.f, 0.f, 0.f};
  f32x4 acc[4][4];
#pragma unroll
  for (int i = 0; i < 4; ++i)
#pragma unroll
    for (int j = 0; j < 4; ++j) acc[i][j] = fzero;
  gemm_core(A, B, 1024, sA, sB, acc);

  const int lane = threadIdx.x & 63, wv = threadIdx.x >> 6;
  const int wm = wv >> 1, wn = wv & 1, q = lane >> 4, cix = lane & 15;
  const int head = mt;
  if (proj == 2) {
#pragma unroll
    for (int mi = 0; mi < 4; ++mi) {
      int rbase = wm * 64 + mi * 16 + q * 4;  // d
#pragma unroll
      for (int ni = 0; ni < 4; ++ni) {
        int col = nt * 128 + wn * 64 + ni * 16 + cix;
        int b = col >> 9, wpos = col & 511;
        size_t base = ((size_t)((cq * 8 + head) * 2 + b) << 16) +
                      ((size_t)rbase << 9) + wpos;
        f32x4 v = acc[mi][ni];
        Vt[base] = f2bf(v[0]);
        Vt[base + 512] = f2bf(v[1]);
        Vt[base + 1024] = f2bf(v[2]);
        Vt[base + 1536] = f2bf(v[3]);
      }
    }
  } else {
    short* QKp = proj ? Kr : Qr;
#pragma unroll
    for (int mi = 0; mi < 4; ++mi) {
      int rbase = wm * 64 + mi * 16 + q * 4;  // d (even)
      int j0 = rbase >> 1;
      float if0 = exp2f(-0.20762050593046f * (float)j0);  // 10000^(-j/64)
      float if1 = exp2f(-0.20762050593046f * (float)(j0 + 1));
#pragma unroll
      for (int ni = 0; ni < 4; ++ni) {
        int col = nt * 128 + wn * 64 + ni * 16 + cix;
        int b = col >> 9, wpos = col & 511;
        float fw = (float)wpos;
        float s0, c0, s1, c1;
        __sincosf(fw * if0, &s0, &c0);
        __sincosf(fw * if1, &s1, &c1);
        f32x4 v = acc[mi][ni];
        short4 pk;
        pk.x = f2bf(v[0] * c0 - v[1] * s0);
        pk.y = f2bf(v[1] * c0 + v[0] * s0);
        pk.z = f2bf(v[2] * c1 - v[3] * s1);
        pk.w = f2bf(v[3] * c1 + v[2] * s1);
        *(short4*)&QKp[((size_t)(((cq * 8 + head) * 2 + b) * 512 + wpos) << 7) +
                       rbase] = pk;
      }
    }
  }
}

// ---------------------------------------------------------------------------
// k_attn (R3 structure, known-good): fused S=QK^T/32+prev (qk written) ->
// softmax (no max subtraction) -> PV -> At. 1-D grid 512, bijective XCD
// swizzle so the 4 qt blocks of one bcn share an XCD (K/V reuse in L2).
//   - Q tile (32 KB) staged to LDS ONCE via global_load_lds with
//     inverse-swizzled SOURCE (linear dest); frag reads XOR-swizzled
//     (byte ^= (row&15)<<4) -> conflict-free ds_read_b128.
//   - K frags direct from global (L2-resident): QK^T phase has NO barriers.
//   - prev_qk double-buffered in 16-float chunks; chunk 0 issued before the
//     MFMA cluster so HBM latency hides under QK^T.
//   - setprio(1) around MFMA clusters.
//   - launch_bounds(256,2): accumulators (128 VGPR) MUST stay in registers;
//     (256,3) spilled them to scratch (R2: VGPR 84, +160MB writes, 2x time).
// ---------------------------------------------------------------------------
__global__ void __launch_bounds__(256, 2) k_attn(
    const short* __restrict__ Qr, const short* __restrict__ Kr,
    const short* __restrict__ Vt, const float* __restrict__ prevqk,
    float* __restrict__ qk, short* __restrict__ At) {
  __shared__ short Qs[128 * 128];   // swizzled Q tile (32 KB)
  __shared__ short Pt[128 * 136];   // P staging (34.8 KB)
  __shared__ float psum[128][2];
  const int tid = threadIdx.x, lane = tid & 63, wv = tid >> 6;
  const int wm = wv >> 1, wn = wv & 1, q = lane >> 4, cix = lane & 15;
  const int bid = blockIdx.x;
  const int lin = (bid & 7) * 64 + (bid >> 3);  // 512 = 8*64, bijective
  const int bcn = lin >> 2, qt = lin & 3;       // 4 qt of a bcn adjacent
  const int b = bcn >> 6, cch = (bcn >> 3) & 7, nh = bcn & 7;
  const size_t qrb = ((size_t)((cch * 8 + nh) * 2 + b)) << 16;
  const size_t rowg0 = (size_t)bcn * 512 + qt * 128;
  const int arow = wm * 64;

  // ---- stage Q once: linear LDS dest, inverse-swizzled global source ----
  {
    const char* Qg = (const char*)(Qr + qrb + ((size_t)qt << 14));
#pragma unroll
    for (int i = 0; i < 8; ++i) {
      int Lb = i * 4096 + wv * 1024;           // wave-uniform dest byte
      int L = Lb + (lane << 4);                // this lane's dest byte
      int src = (L & ~255) | ((L & 255) ^ (((L >> 8) & 15) << 4));
      g2l16(Qg + src, (char*)Qs + Lb);
    }
  }
  __syncthreads();

  const f32x4 fzero = {0.f, 0.f, 0.f, 0.f};
  f32x4 accO[4][4];
  float lsum[4][4];
#pragma unroll
  for (int i = 0; i < 4; ++i)
#pragma unroll
    for (int j = 0; j < 4; ++j) { accO[i][j] = fzero; lsum[i][j] = 0.f; }

  float pvA[16], pvB[16];

#pragma unroll 1
  for (int kt = 0; kt < 4; ++kt) {
    const int colb = kt * 128 + wn * 64 + cix;
    f32x4 accS[4][4];
#pragma unroll
    for (int i = 0; i < 4; ++i)
#pragma unroll
      for (int j = 0; j < 4; ++j) accS[i][j] = fzero;

    // issue prev chunk 0 early: lands while QK^T MFMAs run
#pragma unroll
    for (int ni = 0; ni < 4; ++ni)
#pragma unroll
      for (int r = 0; r < 4; ++r)
        pvA[ni * 4 + r] =
            prevqk[((rowg0 + arow + q * 4 + r) << 9) + colb + ni * 16];

    // ---- S = Q K^T : A-frags from swizzled LDS, B-frags direct global ----
    const short* Kbase = Kr + qrb + ((size_t)kt << 14);
#pragma unroll
    for (int kk = 0; kk < 4; ++kk) {
      s16x8 afr[4], bfr[4];
      const int cb = kk * 64 + q * 16;  // byte col within Q row
#pragma unroll
      for (int ni = 0; ni < 4; ++ni)
        bfr[ni] = *(const s16x8*)(Kbase +
            ((size_t)(wn * 64 + ni * 16 + cix) << 7) + kk * 32 + q * 8);
#pragma unroll
      for (int mi = 0; mi < 4; ++mi) {
        const int row = arow + mi * 16 + cix;
        afr[mi] = *(const s16x8*)((const char*)Qs + row * 256 +
                                  (cb ^ ((row & 15) << 4)));
      }
      __builtin_amdgcn_s_setprio(1);
#pragma unroll
      for (int mi = 0; mi < 4; ++mi)
#pragma unroll
        for (int ni = 0; ni < 4; ++ni)
          accS[mi][ni] = __builtin_amdgcn_mfma_f32_16x16x32_bf16(
              afr[mi], bfr[ni], accS[mi][ni], 0, 0, 0);
      __builtin_amdgcn_s_setprio(0);
    }

    // ---- epilogue: s = S/32 + prev ; qk <- s ; p = exp(s) -> Pt, lsum ----
    auto ldchunk = [&](int mi, float* dst) {
#pragma unroll
      for (int ni = 0; ni < 4; ++ni)
#pragma unroll
        for (int r = 0; r < 4; ++r)
          dst[ni * 4 + r] =
              prevqk[((rowg0 + arow + mi * 16 + q * 4 + r) << 9) +
                     colb + ni * 16];
    };
    auto process = [&](int mi, const float* pv) {
      float rs[4] = {0.f, 0.f, 0.f, 0.f};
#pragma unroll
      for (int ni = 0; ni < 4; ++ni)
#pragma unroll
        for (int r = 0; r < 4; ++r) {
          float s = accS[mi][ni][r] * 0.03125f + pv[ni * 4 + r];
          qk[((rowg0 + arow + mi * 16 + q * 4 + r) << 9) + colb + ni * 16] = s;
          float p = __expf(s);
          rs[r] += p;
          Pt[(arow + mi * 16 + q * 4 + r) * 136 + wn * 64 + ni * 16 + cix] =
              f2bf(p);
        }
#pragma unroll
      for (int r = 0; r < 4; ++r) lsum[mi][r] += rs[r];
    };
    ldchunk(1, pvB);
    process(0, pvA);
    ldchunk(2, pvA);
    process(1, pvB);
    ldchunk(3, pvB);
    process(2, pvA);
    process(3, pvB);

    __syncthreads();  // Pt visible to all waves

    // ---- PV: A = Pt (LDS), B = Vt (global, L2-resident) ----
#pragma unroll
    for (int s4 = 0; s4 < 4; ++s4) {
      s16x8 afr[4], bfr[4];
#pragma unroll
      for (int i = 0; i < 4; ++i)
        afr[i] =
            *(const s16x8*)&Pt[(arow + i * 16 + cix) * 136 + s4 * 32 + q * 8];
#pragma unroll
      for (int i = 0; i < 4; ++i)
        bfr[i] = *(const s16x8*)&Vt[qrb +
                                    ((size_t)(wn * 64 + i * 16 + cix) << 9) +
                                    kt * 128 + s4 * 32 + q * 8];
      __builtin_amdgcn_s_setprio(1);
#pragma unroll
      for (int i = 0; i < 4; ++i)
#pragma unroll
        for (int j = 0; j < 4; ++j)
          accO[i][j] = __builtin_amdgcn_mfma_f32_16x16x32_bf16(
              afr[i], bfr[j], accO[i][j], 0, 0, 0);
      __builtin_amdgcn_s_setprio(0);
    }
    __syncthreads();  // PV reads done -> Pt reusable next kt
  }

  // combine row sums across cix lanes and the two wn waves
#pragma unroll
  for (int mi = 0; mi < 4; ++mi)
#pragma unroll
    for (int r = 0; r < 4; ++r) {
      float se = lsum[mi][r];
      se += __shfl_xor(se, 1);
      se += __shfl_xor(se, 2);
      se += __shfl_xor(se, 4);
      se += __shfl_xor(se, 8);
      if (cix == 0) psum[arow + mi * 16 + q * 4 + r][wn] = se;
    }
  __syncthreads();
  // normalize and store At[c][b*512+wq][nh*128+d]
#pragma unroll
  for (int mi = 0; mi < 4; ++mi) {
    int rl = arow + mi * 16 + q * 4;
    float iL[4];
#pragma unroll
    for (int r = 0; r < 4; ++r)
      iL[r] = 1.0f / (psum[rl + r][0] + psum[rl + r][1]);
    int wq = qt * 128 + rl;
#pragma unroll
    for (int ni = 0; ni < 4; ++ni) {
      int dl = wn * 64 + ni * 16 + cix;
      size_t ob = (((size_t)cch << 10) + b * 512 + wq) * 1024 + nh * 128 + dl;
      f32x4 v = accO[mi][ni];
      At[ob] = f2bf(v[0] * iL[0]);
      At[ob + 1024] = f2bf(v[1] * iL[1]);
      At[ob + 2048] = f2bf(v[2] * iL[2]);
      At[ob + 3072] = f2bf(v[3] * iL[3]);
    }
  }
}

// ---------------------------------------------------------------------------
// k_out: role-swapped GEMM: C'[col][f] = sum_h At[col][h]*Wo[f][h]. XCD-
// clustered 1-D grid of 512. Stores float4 along w.
// ---------------------------------------------------------------------------
__global__ void __launch_bounds__(256) k_out(
    const short* __restrict__ At, const short* __restrict__ Wob,
    float* __restrict__ outp) {
  __shared__ short sA[2 * 128 * 32], sB[2 * 128 * 32];
  const int L = blockIdx.x;
  const int lin = (L & 7) * 64 + (L >> 3);
  const int c = lin >> 6;
  const int t = lin & 63;
  const int mt = t >> 3, nt = t & 7;
  const short* A = At + ((size_t)c << 20) + ((size_t)mt << 17);
  const short* B = Wob + ((size_t)c << 20) + ((size_t)nt << 17);
  const f32x4 fzero = {0.f, 0.f, 0.f, 0.f};
  f32x4 acc[4][4];
#pragma unroll
  for (int i = 0; i < 4; ++i)
#pragma unroll
    for (int j = 0; j < 4; ++j) acc[i][j] = fzero;
  gemm_core(A, B, 1024, sA, sB, acc);

  const int lane = threadIdx.x & 63, wv = threadIdx.x >> 6;
  const int wm = wv >> 1, wn = wv & 1, q = lane >> 4, cix = lane & 15;
#pragma unroll
  for (int mi = 0; mi < 4; ++mi) {
    int colm = mt * 128 + wm * 64 + mi * 16 + q * 4;
    int b = colm >> 9, w = colm & 511;
#pragma unroll
    for (int ni = 0; ni < 4; ++ni) {
      int f = nt * 128 + wn * 64 + ni * 16 + cix;
      f32x4 v = acc[mi][ni];
      float4 st; st.x = v[0]; st.y = v[1]; st.z = v[2]; st.w = v[3];
      *(float4*)&outp[((((size_t)b * 8 + c) << 10) + f) * 512 + w] = st;
    }
  }
}

// ---------------------------------------------------------------------------
extern "C" void kernel_launch(void* const* d_in, const int* in_sizes, int n_in,
                              void* d_out, int out_size, void* d_ws,
                              size_t ws_size, hipStream_t stream) {
  const float* x = (const float*)d_in[0];
  const float* prevqk = (const float*)d_in[1];
  const float* wqc = (const float*)d_in[2];
  const float* bqc = (const float*)d_in[3];
  const float* wql = (const float*)d_in[4];
  const float* wkc = (const float*)d_in[5];
  const float* bkc = (const float*)d_in[6];
  const float* wkl = (const float*)d_in[7];
  const float* wvc = (const float*)d_in[8];
  const float* bvc = (const float*)d_in[9];
  const float* wvl = (const float*)d_in[10];
  const float* wol = (const float*)d_in[11];
  float* outp = (float*)d_out;
  float* qk = outp + 8388608;  // out is B*C*F*W floats, then qk

  char* ws = (char*)d_ws;
  short* Wb = (short*)ws;                  // 67,108,864 B (4 weight mats bf16)
  short* Yt = (short*)(ws + 67108864);     // 50,331,648 B
  short* Qr = (short*)(ws + 117440512);    // 16,777,216 B
  short* Kr = (short*)(ws + 134217728);    // 16,777,216 B
  short* Vt = (short*)(ws + 150994944);    // 16,777,216 B
  short* At = (short*)(ws + 67108864);     // alias Yt (dead after k_qkv)
  short* Wob = Wb + ((size_t)24 << 20);    // wo segment of Wb

  k_cvt<<<dim3(8192), 256, 0, stream>>>(wql, wkl, wvl, wol, Wb);
  k_conv<<<dim3(16, 32, 2), 256, 0, stream>>>(x, wqc, bqc, wkc, bkc, wvc, bvc, Yt);
  k_qkv<<<dim3(1536), 256, 0, stream>>>(Wb, Yt, Qr, Kr, Vt);
  k_attn<<<dim3(512), 256, 0, stream>>>(Qr, Kr, Vt, prevqk, qk, At);
  k_out<<<dim3(512), 256, 0, stream>>>(At, Wob, outp);
}